// Round 1
// baseline (101.483 us; speedup 1.0000x reference)
//
#include <hip/hip_runtime.h>

#define EPS 5e-4f
#define LOG2E 1.4426950408889634f
#define BATCH 32
#define N 2048

// native 2^x (v_exp_f32)
__device__ __forceinline__ float fast_exp2(float x) {
#if __has_builtin(__builtin_amdgcn_exp2f)
    return __builtin_amdgcn_exp2f(x);
#else
    extern "C" __device__ float __ocml_native_exp2_f32(float);
    return __ocml_native_exp2_f32(x);
#endif
}

// Kernel A: per-row maxDCG via 5-bin histogram (labels are ints 0..4), plus
// zero d_out. maxDCG = sum over descending-sorted labels of (2^v - 1)/log2(1+rank).
__global__ __launch_bounds__(256) void maxdcg_kernel(const float* __restrict__ y_true,
                                                     float* __restrict__ ws,
                                                     float* __restrict__ out) {
    const int row = blockIdx.x;
    const int tid = threadIdx.x;
    __shared__ int cnt[5];
    __shared__ float red[256];
    if (tid < 5) cnt[tid] = 0;
    __syncthreads();

    const float* yt = y_true + row * N;
    int c1 = 0, c2 = 0, c3 = 0, c4 = 0;
    for (int i = tid; i < N; i += 256) {
        int v = (int)yt[i];
        c1 += (v == 1); c2 += (v == 2); c3 += (v == 3); c4 += (v == 4);
    }
    atomicAdd(&cnt[1], c1);
    atomicAdd(&cnt[2], c2);
    atomicAdd(&cnt[3], c3);
    atomicAdd(&cnt[4], c4);
    __syncthreads();

    const int cum4 = cnt[4];
    const int cum3 = cum4 + cnt[3];
    const int cum2 = cum3 + cnt[2];
    const int cum1 = cum2 + cnt[1];

    float part = 0.f;
    for (int r = tid + 1; r <= N; r += 256) {
        float g = (r <= cum4) ? 15.f : (r <= cum3) ? 7.f
                : (r <= cum2) ? 3.f  : (r <= cum1) ? 1.f : 0.f;
        if (g > 0.f) part += g / __log2f((float)(1 + r));
    }
    red[tid] = part;
    __syncthreads();
    for (int s = 128; s > 0; s >>= 1) {
        if (tid < s) red[tid] += red[tid + s];
        __syncthreads();
    }
    if (tid == 0) {
        ws[row] = fmaxf(red[0], EPS);
        if (row == 0) out[0] = 0.f;  // d_out is poisoned 0xAA each call
    }
}

// Kernel B: one block = (row, chunk of 64 k's). 4 threads per k split the
// 2048-long l-sweep into 4 slices of 512. LDS-broadcast reads of p_row.
__global__ __launch_bounds__(256) void ndcg_kernel(const float* __restrict__ y_pred,
                                                   const float* __restrict__ y_true,
                                                   const float* __restrict__ ws,
                                                   float* __restrict__ out) {
    const int row   = blockIdx.y;
    const int chunk = blockIdx.x;   // 0..31 -> 64 k's each
    const int tid   = threadIdx.x;
    __shared__ float p[N];
    __shared__ float red[256];

    const float* yp = y_pred + row * N;
    // stage the full row: 512 float4's by 256 threads, coalesced
    for (int i = tid; i < N / 4; i += 256) {
        ((float4*)p)[i] = ((const float4*)yp)[i];
    }
    __syncthreads();

    const int klocal = tid & 63;
    const int k = chunk * 64 + klocal;
    const int slice = tid >> 6;            // 0..3
    const float a = p[k] * LOG2E;          // exponent = a - p_l*LOG2E => e^{p_k-p_l}

    float acc = 0.f;
    const int lbase = slice * (N / 4);     // 512-wide slice
#pragma unroll 1
    for (int l = lbase; l < lbase + N / 4; l += 8) {
        float4 x0 = *(const float4*)&p[l];
        float4 x1 = *(const float4*)&p[l + 4];
        float e[8] = {x0.x, x0.y, x0.z, x0.w, x1.x, x1.y, x1.z, x1.w};
#pragma unroll
        for (int j = 0; j < 8; ++j) {
            // sigmoid(p_l - p_k) = 1 / (1 + e^{p_k - p_l})
            float u = fast_exp2(__builtin_fmaf(e[j], -LOG2E, a));
            float s = __builtin_amdgcn_rcpf(1.0f + u);
            acc += fmaxf(s, EPS);
        }
    }
    red[tid] = acc;
    __syncthreads();

    if (tid < 64) {   // one full wave; k == chunk*64 + tid here
        float total = red[tid] + red[tid + 64] + red[tid + 128] + red[tid + 192];
        // total includes the self term sigma(0)=0.5; pos = 1 + (total - 0.5)
        float pos = 0.5f + total;
        float aD  = __log2f(1.0f + pos);
        float tk  = y_true[row * N + k];
        float g   = (fast_exp2(tk) - 1.0f) / ws[row];
        float contrib = g / aD;
#pragma unroll
        for (int off = 32; off > 0; off >>= 1)
            contrib += __shfl_down(contrib, off);
        if (tid == 0) atomicAdd(out, contrib * (1.0f / BATCH));
    }
}

extern "C" void kernel_launch(void* const* d_in, const int* in_sizes, int n_in,
                              void* d_out, int out_size, void* d_ws, size_t ws_size,
                              hipStream_t stream) {
    const float* y_pred = (const float*)d_in[0];
    const float* y_true = (const float*)d_in[1];
    float* out = (float*)d_out;
    float* ws  = (float*)d_ws;   // 32 floats: per-row maxDCG

    maxdcg_kernel<<<dim3(BATCH), dim3(256), 0, stream>>>(y_true, ws, out);
    ndcg_kernel<<<dim3(32, BATCH), dim3(256), 0, stream>>>(y_pred, y_true, ws, out);
}